// Round 1
// baseline (393.890 us; speedup 1.0000x reference)
//
#include <hip/hip_runtime.h>
#include <math.h>
#include <stdint.h>

// ---------------------------------------------------------------------------
// SIRnet: encoder (8192->128->64->2) -> dopri5 SIR solve (T=8192, 4 substeps)
//         -> decoder (3->64->128->8192) with ReLU, fp32 semantics.
//
// Round 4:
//  - GEMM: K split into 4 chunks of 32; per chunk stage {Ahi,Alo,Bhi,Blo}
//    ONCE (32 KB) and run all 3 split-bf16 passes with fragment reuse.
//    Staged bytes/block 192->128 KB, barrier pairs 6->4. XOR swizzle kept
//    (4-slot rows). XCD-aware block swizzle for L2 locality (4096%8==0).
//  - wprep fused into the enc1 dispatch (192 blocks) -> 4 dispatches total.
//  - ODE cascade unchanged (validated in earlier rounds).
// ---------------------------------------------------------------------------

typedef __attribute__((ext_vector_type(8))) short short8_t;
typedef __attribute__((ext_vector_type(4))) float f32x4;

#define DT_C 0.001220703125f  // 10/8192, exact in fp32

__device__ __forceinline__ unsigned short f2bf_rn(float f) {
  unsigned int u = __float_as_uint(f);
  unsigned int r = (u + 0x7fffu + ((u >> 16) & 1u)) >> 16;
  return (unsigned short)r;
}
__device__ __forceinline__ float bf2f(unsigned short h) {
  return __uint_as_float(((unsigned int)h) << 16);
}

// global -> LDS direct copy, 16 B per lane. LDS dest = uniform base + lane*16.
__device__ __forceinline__ void gl2lds16(const void* g, void* lds_base) {
  __builtin_amdgcn_global_load_lds(
      (const __attribute__((address_space(1))) unsigned int*)(uintptr_t)g,
      (__attribute__((address_space(3))) unsigned int*)(uintptr_t)lds_base,
      16, 0, 0);
}

// ---------------- SIR / dopri5 -------------------------------------------

__device__ __forceinline__ void f_sir(float beta, float gamma,
                                      const float y[3], float d[3]) {
  float SI = y[0] * y[1];
  d[0] = -beta * SI;
  d[1] = beta * SI - gamma * y[1];
  d[2] = gamma * y[1];
}

__device__ __forceinline__ void dopri5_step(float beta, float gamma,
                                            float y[3], float dt) {
  float k1[3], k2[3], k3[3], k4[3], k5[3], k6[3], tmp[3];
  f_sir(beta, gamma, y, k1);
#pragma unroll
  for (int c = 0; c < 3; ++c)
    tmp[c] = y[c] + dt * (0.2f * k1[c]);
  f_sir(beta, gamma, tmp, k2);
#pragma unroll
  for (int c = 0; c < 3; ++c)
    tmp[c] = y[c] + dt * (0.075f * k1[c] + 0.225f * k2[c]);
  f_sir(beta, gamma, tmp, k3);
#pragma unroll
  for (int c = 0; c < 3; ++c)
    tmp[c] = y[c] + dt * ((44.0f / 45.0f) * k1[c] + (-56.0f / 15.0f) * k2[c] +
                          (32.0f / 9.0f) * k3[c]);
  f_sir(beta, gamma, tmp, k4);
#pragma unroll
  for (int c = 0; c < 3; ++c)
    tmp[c] = y[c] + dt * ((19372.0f / 6561.0f) * k1[c] +
                          (-25360.0f / 2187.0f) * k2[c] +
                          (64448.0f / 6561.0f) * k3[c] +
                          (-212.0f / 729.0f) * k4[c]);
  f_sir(beta, gamma, tmp, k5);
#pragma unroll
  for (int c = 0; c < 3; ++c)
    tmp[c] = y[c] + dt * ((9017.0f / 3168.0f) * k1[c] +
                          (-355.0f / 33.0f) * k2[c] +
                          (46732.0f / 5247.0f) * k3[c] +
                          (49.0f / 176.0f) * k4[c] +
                          (-5103.0f / 18656.0f) * k5[c]);
  f_sir(beta, gamma, tmp, k6);
#pragma unroll
  for (int c = 0; c < 3; ++c)
    y[c] = y[c] + dt * ((35.0f / 384.0f) * k1[c] +
                        (500.0f / 1113.0f) * k3[c] +
                        (125.0f / 192.0f) * k4[c] +
                        (-2187.0f / 6784.0f) * k5[c] +
                        (11.0f / 84.0f) * k6[c]);
}

// ---------------- Fused: enc1 (blocks 0..63) + W3 pack (blocks 64..191) ----
__global__ __launch_bounds__(256) void pre_kernel(
    const float* __restrict__ x, const float* __restrict__ w1,
    float* __restrict__ partial,
    const float* __restrict__ w3, unsigned short* __restrict__ Wt) {
  __shared__ __align__(16) float smem[128 * 65];  // 33 KB, shared by branches
  int tid = threadIdx.x;
  if (blockIdx.x < 64) {
    // ---- encoder layer 1 partial sums ----
    float4* sh = (float4*)smem;
    int j4 = tid & 31, kh = tid >> 5;
    int kbase = blockIdx.x * 128 + kh * 16;
    float4 a; a.x = 0.f; a.y = 0.f; a.z = 0.f; a.w = 0.f;
#pragma unroll
    for (int r = 0; r < 16; ++r) {
      int k = kbase + r;
      float xv = x[k];
      float4 wv = *(const float4*)(w1 + (size_t)k * 128 + j4 * 4);
      a.x = fmaf(xv, wv.x, a.x);
      a.y = fmaf(xv, wv.y, a.y);
      a.z = fmaf(xv, wv.z, a.z);
      a.w = fmaf(xv, wv.w, a.w);
    }
    sh[tid] = a;
    __syncthreads();
    if (tid < 32) {
      float4 s = sh[tid];
#pragma unroll
      for (int h = 1; h < 8; ++h) {
        float4 o = sh[h * 32 + tid];
        s.x += o.x; s.y += o.y; s.z += o.z; s.w += o.w;
      }
      *(float4*)(partial + blockIdx.x * 128 + tid * 4) = s;
    }
  } else {
    // ---- W3 pack (bf16 hi/lo, linear layout, validated Round 2) ----
    float* tl = smem;
    int n0 = (blockIdx.x - 64) * 64;
#pragma unroll
    for (int e = 0; e < 32; ++e) {
      int idx = e * 256 + tid;
      int k = idx >> 6, c = idx & 63;
      tl[k * 65 + c] = w3[(size_t)k * 8192 + n0 + c];
    }
    __syncthreads();
    int nl = tid >> 2, q = tid & 3;
#pragma unroll
    for (int w = 0; w < 4; ++w) {
      int k0 = q * 32 + w * 8;
      short8_t vh, vl;
#pragma unroll
      for (int jj = 0; jj < 8; ++jj) {
        float v = tl[(k0 + jj) * 65 + nl];
        unsigned short h = f2bf_rn(v);
        vh[jj] = (short)h;
        vl[jj] = (short)f2bf_rn(v - bf2f(h));
      }
      *(short8_t*)(Wt + (size_t)(n0 + nl) * 256 + k0) = vh;
      *(short8_t*)(Wt + (size_t)(n0 + nl) * 256 + 128 + k0) = vl;
    }
  }
}

// ---------------- prep: enc2 + coarse ODE cascade -------------------------
__global__ __launch_bounds__(256) void prep_kernel(
    const float* __restrict__ partial, const float* __restrict__ b1,
    const float* __restrict__ w2, const float* __restrict__ b2,
    const float* __restrict__ w3, const float* __restrict__ b3,
    float* __restrict__ bg, float* __restrict__ ys) {
  __shared__ float h1s[128];
  __shared__ float h2s[64];
  __shared__ float bgs[2];
  __shared__ float Y0[16][3];
  __shared__ float Y1[256][3];
  int t = threadIdx.x;
  if (t < 128) {
    float s = b1[t];
    for (int b = 0; b < 64; ++b) s += partial[b * 128 + t];
    h1s[t] = fmaxf(s, 0.0f);
  }
  __syncthreads();
  if (t < 64) {
    float a = b2[t];
    for (int k = 0; k < 128; ++k) a = fmaf(h1s[k], w2[k * 64 + t], a);
    h2s[t] = fmaxf(a, 0.0f);
  }
  __syncthreads();
  if (t < 2) {
    float p = b3[t];
    for (int k = 0; k < 64; ++k) p = fmaf(h2s[k], w3[k * 2 + t], p);
    bgs[t] = p;
    bg[t] = p;
  }
  __syncthreads();
  float beta = bgs[0], gamma = bgs[1];
  if (t == 0) {
    float y[3] = {0.99f, 0.01f, 0.0f};
    Y0[0][0] = y[0]; Y0[0][1] = y[1]; Y0[0][2] = y[2];
    for (int j = 1; j < 16; ++j) {
      dopri5_step(beta, gamma, y, 512.0f * DT_C);
      Y0[j][0] = y[0]; Y0[j][1] = y[1]; Y0[j][2] = y[2];
    }
  }
  __syncthreads();
  if (t < 16) {
    float y[3] = {Y0[t][0], Y0[t][1], Y0[t][2]};
    Y1[t * 16][0] = y[0]; Y1[t * 16][1] = y[1]; Y1[t * 16][2] = y[2];
    for (int s = 1; s < 16; ++s) {
      dopri5_step(beta, gamma, y, 32.0f * DT_C);
      Y1[t * 16 + s][0] = y[0]; Y1[t * 16 + s][1] = y[1]; Y1[t * 16 + s][2] = y[2];
    }
  }
  __syncthreads();
  {
    float y[3] = {Y1[t][0], Y1[t][1], Y1[t][2]};
    ys[(t * 8) * 3 + 0] = y[0]; ys[(t * 8) * 3 + 1] = y[1]; ys[(t * 8) * 3 + 2] = y[2];
    for (int s = 1; s < 8; ++s) {
      dopri5_step(beta, gamma, y, 4.0f * DT_C);
      ys[(t * 8 + s) * 3 + 0] = y[0];
      ys[(t * 8 + s) * 3 + 1] = y[1];
      ys[(t * 8 + s) * 3 + 2] = y[2];
    }
  }
}

// ---------------- dec12f: fine ODE + decoder small layers + A pack --------
__global__ __launch_bounds__(256) void dec12f_kernel(
    const float* __restrict__ bg, const float* __restrict__ ys,
    const float* __restrict__ w1, const float* __restrict__ b1,
    const float* __restrict__ w2, const float* __restrict__ b2,
    unsigned short* __restrict__ Apack) {
  __shared__ float sols[128 * 4];
  __shared__ float w1s[192];
  __shared__ float b1s[64];
  __shared__ float b2s[128];
  __shared__ float h1s[128 * 66];
  int tid = threadIdx.x;
  int i0 = blockIdx.x * 128;
  if (tid < 192) w1s[tid] = w1[tid];
  if (tid < 64) b1s[tid] = b1[tid];
  if (tid < 128) b2s[tid] = b2[tid];
  if (tid < 33) {
    const float h = 0.25f * DT_C;
    float beta = bg[0], gamma = bg[1];
    int w = blockIdx.x * 32 + tid - 1;
    if (w < 0) {
      sols[0] = 0.99f; sols[1] = 0.01f; sols[2] = 0.0f;
    } else {
      float y[3] = {ys[w * 3 + 0], ys[w * 3 + 1], ys[w * 3 + 2]};
#pragma unroll
      for (int iv = 0; iv < 4; ++iv) {
        dopri5_step(beta, gamma, y, h);
        dopri5_step(beta, gamma, y, h);
        dopri5_step(beta, gamma, y, h);
        dopri5_step(beta, gamma, y, h);
        int local = 4 * w + iv + 1 - i0;
        if (local >= 0 && local < 128) {
          sols[local * 4 + 0] = y[0];
          sols[local * 4 + 1] = y[1];
          sols[local * 4 + 2] = y[2];
        }
      }
    }
  }
  __syncthreads();
#pragma unroll
  for (int e = 0; e < 32; ++e) {
    int idx = e * 256 + tid;
    int i = idx >> 6, j = idx & 63;
    float v = b1s[j];
    v = fmaf(sols[i * 4 + 0], w1s[j], v);
    v = fmaf(sols[i * 4 + 1], w1s[64 + j], v);
    v = fmaf(sols[i * 4 + 2], w1s[128 + j], v);
    h1s[i * 66 + j] = fmaxf(v, 0.0f);
  }
  __syncthreads();
  int tx = tid & 15, ty = tid >> 4;
  float acc[8][8];
#pragma unroll
  for (int a = 0; a < 8; ++a)
#pragma unroll
    for (int b = 0; b < 8; ++b) acc[a][b] = 0.0f;
  for (int j = 0; j < 64; ++j) {
    float a[8];
#pragma unroll
    for (int mm = 0; mm < 8; ++mm) a[mm] = h1s[(ty * 8 + mm) * 66 + j];
    float4 q0 = *(const float4*)(w2 + j * 128 + tx * 8);
    float4 q1 = *(const float4*)(w2 + j * 128 + tx * 8 + 4);
    float b[8] = {q0.x, q0.y, q0.z, q0.w, q1.x, q1.y, q1.z, q1.w};
#pragma unroll
    for (int mm = 0; mm < 8; ++mm)
#pragma unroll
      for (int nn = 0; nn < 8; ++nn)
        acc[mm][nn] = fmaf(a[mm], b[nn], acc[mm][nn]);
  }
#pragma unroll
  for (int mm = 0; mm < 8; ++mm) {
    int row = i0 + ty * 8 + mm;
    short8_t vh, vl;
#pragma unroll
    for (int nn = 0; nn < 8; ++nn) {
      float v = fmaxf(acc[mm][nn] + b2s[tx * 8 + nn], 0.0f);
      unsigned short h = f2bf_rn(v);
      vh[nn] = (short)h;
      vl[nn] = (short)f2bf_rn(v - bf2f(h));
    }
    *(short8_t*)(Apack + (size_t)row * 256 + tx * 8) = vh;
    *(short8_t*)(Apack + (size_t)row * 256 + 128 + tx * 8) = vl;
  }
}

// ---------------- Big GEMM (bf16 split MFMA, chunked staging) -------------
// out = relu(h2 @ W3 + b3) via Ahi*Bhi + Ahi*Blo + Alo*Bhi.
// A=Apack[8192][256], B=Wt[8192][256] (hi[128] | lo[128] shorts per row).
// K processed as 4 chunks of 32 shorts; per chunk stage Ahi/Alo/Bhi/Blo once
// (4 x 8 KB LDS), then all 3 passes with A-hi/B-hi fragment reuse.
// Row = 4 slots of 8 shorts; logical chunk g stored at slot g^(r&3).
// XCD-aware block swizzle: 4096 blocks, 512 consecutive per XCD share the
// same B-panel (L2-hot) and stream A (4 MB = one XCD L2).
__global__ __launch_bounds__(256) void gemm_bf16_kernel(
    const unsigned short* __restrict__ A, const unsigned short* __restrict__ B,
    const float* __restrict__ bias, float* __restrict__ out) {
  __shared__ unsigned short Ah[128 * 32];
  __shared__ unsigned short Al[128 * 32];
  __shared__ unsigned short Bh[128 * 32];
  __shared__ unsigned short Bl[128 * 32];
  int tid = threadIdx.x;
  int bid = blockIdx.x;
  int swz = (bid & 7) * 512 + (bid >> 3);   // bijective, 4096 % 8 == 0
  int by = swz & 63, bx = swz >> 6;
  int m0 = by * 128;
  int n0 = bx * 128;
  int lane = tid & 63, wave = tid >> 6;
  int wm = (wave >> 1) * 64, wn = (wave & 1) * 64;
  int lrow = lane & 15, lgrp = lane >> 4;
  int lr4 = lane >> 2, lp = lane & 3;  // staging: row-in-16, slot

  f32x4 acc[4][4];
  f32x4 z = {0.0f, 0.0f, 0.0f, 0.0f};
#pragma unroll
  for (int mi = 0; mi < 4; ++mi)
#pragma unroll
    for (int ni = 0; ni < 4; ++ni) acc[mi][ni] = z;

  for (int c = 0; c < 4; ++c) {
    int kin = c * 32;
#pragma unroll
    for (int i = 0; i < 2; ++i) {
      int seg = wave * 2 + i;           // 8 segments of 16 rows
      int r = seg * 16 + lr4;           // tile row this lane fetches
      int g = lp ^ (r & 3);             // logical chunk for slot lp
      const unsigned short* ar = A + (size_t)(m0 + r) * 256 + kin + g * 8;
      const unsigned short* br = B + (size_t)(n0 + r) * 256 + kin + g * 8;
      gl2lds16(ar, &Ah[seg * 512]);         // hi half
      gl2lds16(ar + 128, &Al[seg * 512]);   // lo half
      gl2lds16(br, &Bh[seg * 512]);
      gl2lds16(br + 128, &Bl[seg * 512]);
    }
    __syncthreads();

    short8_t ah[4], bh[4];
#pragma unroll
    for (int mi = 0; mi < 4; ++mi) {
      int r = wm + mi * 16 + lrow;
      int p = lgrp ^ (r & 3);
      ah[mi] = *(const short8_t*)(&Ah[r * 32 + p * 8]);
    }
#pragma unroll
    for (int ni = 0; ni < 4; ++ni) {
      int r = wn + ni * 16 + lrow;
      int p = lgrp ^ (r & 3);
      bh[ni] = *(const short8_t*)(&Bh[r * 32 + p * 8]);
    }
    // pass 0: Ahi x Bhi
#pragma unroll
    for (int mi = 0; mi < 4; ++mi)
#pragma unroll
      for (int ni = 0; ni < 4; ++ni)
        acc[mi][ni] = __builtin_amdgcn_mfma_f32_16x16x32_bf16(
            ah[mi], bh[ni], acc[mi][ni], 0, 0, 0);
    // pass 1: Ahi x Blo (reuse ah)
    {
      short8_t bl[4];
#pragma unroll
      for (int ni = 0; ni < 4; ++ni) {
        int r = wn + ni * 16 + lrow;
        int p = lgrp ^ (r & 3);
        bl[ni] = *(const short8_t*)(&Bl[r * 32 + p * 8]);
      }
#pragma unroll
      for (int mi = 0; mi < 4; ++mi)
#pragma unroll
        for (int ni = 0; ni < 4; ++ni)
          acc[mi][ni] = __builtin_amdgcn_mfma_f32_16x16x32_bf16(
              ah[mi], bl[ni], acc[mi][ni], 0, 0, 0);
    }
    // pass 2: Alo x Bhi (reuse bh)
    {
      short8_t al[4];
#pragma unroll
      for (int mi = 0; mi < 4; ++mi) {
        int r = wm + mi * 16 + lrow;
        int p = lgrp ^ (r & 3);
        al[mi] = *(const short8_t*)(&Al[r * 32 + p * 8]);
      }
#pragma unroll
      for (int mi = 0; mi < 4; ++mi)
#pragma unroll
        for (int ni = 0; ni < 4; ++ni)
          acc[mi][ni] = __builtin_amdgcn_mfma_f32_16x16x32_bf16(
              al[mi], bh[ni], acc[mi][ni], 0, 0, 0);
    }
    __syncthreads();
  }

  float bv[4];
#pragma unroll
  for (int ni = 0; ni < 4; ++ni) bv[ni] = bias[n0 + wn + ni * 16 + lrow];
#pragma unroll
  for (int mi = 0; mi < 4; ++mi)
#pragma unroll
    for (int ni = 0; ni < 4; ++ni) {
      int col = n0 + wn + ni * 16 + lrow;
#pragma unroll
      for (int r = 0; r < 4; ++r) {
        int row = m0 + wm + mi * 16 + lgrp * 4 + r;
        out[(size_t)row * 8192 + col] = fmaxf(acc[mi][ni][r] + bv[ni], 0.0f);
      }
    }
}

// ---------------- Launch --------------------------------------------------

extern "C" void kernel_launch(void* const* d_in, const int* in_sizes, int n_in,
                              void* d_out, int out_size, void* d_ws, size_t ws_size,
                              hipStream_t stream) {
  const float* x      = (const float*)d_in[0];
  const float* enc_w1 = (const float*)d_in[2];
  const float* enc_b1 = (const float*)d_in[3];
  const float* enc_w2 = (const float*)d_in[4];
  const float* enc_b2 = (const float*)d_in[5];
  const float* enc_w3 = (const float*)d_in[6];
  const float* enc_b3 = (const float*)d_in[7];
  const float* dec_w1 = (const float*)d_in[8];
  const float* dec_b1 = (const float*)d_in[9];
  const float* dec_w2 = (const float*)d_in[10];
  const float* dec_b2 = (const float*)d_in[11];
  const float* dec_w3 = (const float*)d_in[12];
  const float* dec_b3 = (const float*)d_in[13];
  float* out = (float*)d_out;

  // ws layout: bg[2] @0, partial[64*128] @64, ys[2048*3] @8320 (floats);
  // Apack 4 MB @ byte 65536; Wt 4 MB @ byte 4259840. Total ~8.26 MB.
  float* ws      = (float*)d_ws;
  float* bg      = ws;
  float* partial = ws + 64;
  float* ys      = ws + 8320;
  unsigned short* Apack = (unsigned short*)((char*)d_ws + 65536);
  unsigned short* Wt    = (unsigned short*)((char*)d_ws + 65536 + 4194304);

  hipLaunchKernelGGL(pre_kernel, dim3(192), dim3(256), 0, stream,
                     x, enc_w1, partial, dec_w3, Wt);
  hipLaunchKernelGGL(prep_kernel, dim3(1), dim3(256), 0, stream,
                     partial, enc_b1, enc_w2, enc_b2, enc_w3, enc_b3, bg, ys);
  hipLaunchKernelGGL(dec12f_kernel, dim3(64), dim3(256), 0, stream,
                     bg, ys, dec_w1, dec_b1, dec_w2, dec_b2, Apack);
  hipLaunchKernelGGL(gemm_bf16_kernel, dim3(4096), dim3(256), 0, stream,
                     Apack, Wt, dec_b3, out);
}

// Round 2
// 383.328 us; speedup vs baseline: 1.0276x; 1.0276x over previous
//
#include <hip/hip_runtime.h>
#include <math.h>
#include <stdint.h>

// ---------------------------------------------------------------------------
// SIRnet: encoder (8192->128->64->2) -> dopri5 SIR solve (T=8192, 4 substeps)
//         -> decoder (3->64->128->8192) with ReLU, fp32 semantics.
//
// Round 5:
//  - GEMM: 256x256 tile, 8 waves (512 thr). K = 4 chunks of 32 shorts,
//    double-buffered LDS (128 KB): STAGE(c+1) issued BEFORE compute of c,
//    ONE __syncthreads per chunk (implicit vmcnt(0) drain lands after the
//    MFMA phase). Staged L2 bytes halved vs 128^2 (512->256 MB total).
//    Same split-bf16 pass order (AhBh, AhBl, AlBh) -> numerics identical.
//  - XCD swizzle on 1024 blocks: each XCD owns 4 n-panels (B stays L2-hot),
//    streams A.
//  - pre/prep/dec12f unchanged (validated).
// ---------------------------------------------------------------------------

typedef __attribute__((ext_vector_type(8))) short short8_t;
typedef __attribute__((ext_vector_type(4))) float f32x4;

#define DT_C 0.001220703125f  // 10/8192, exact in fp32

__device__ __forceinline__ unsigned short f2bf_rn(float f) {
  unsigned int u = __float_as_uint(f);
  unsigned int r = (u + 0x7fffu + ((u >> 16) & 1u)) >> 16;
  return (unsigned short)r;
}
__device__ __forceinline__ float bf2f(unsigned short h) {
  return __uint_as_float(((unsigned int)h) << 16);
}

// global -> LDS direct copy, 16 B per lane. LDS dest = uniform base + lane*16.
__device__ __forceinline__ void gl2lds16(const void* g, void* lds_base) {
  __builtin_amdgcn_global_load_lds(
      (const __attribute__((address_space(1))) unsigned int*)(uintptr_t)g,
      (__attribute__((address_space(3))) unsigned int*)(uintptr_t)lds_base,
      16, 0, 0);
}

// ---------------- SIR / dopri5 -------------------------------------------

__device__ __forceinline__ void f_sir(float beta, float gamma,
                                      const float y[3], float d[3]) {
  float SI = y[0] * y[1];
  d[0] = -beta * SI;
  d[1] = beta * SI - gamma * y[1];
  d[2] = gamma * y[1];
}

__device__ __forceinline__ void dopri5_step(float beta, float gamma,
                                            float y[3], float dt) {
  float k1[3], k2[3], k3[3], k4[3], k5[3], k6[3], tmp[3];
  f_sir(beta, gamma, y, k1);
#pragma unroll
  for (int c = 0; c < 3; ++c)
    tmp[c] = y[c] + dt * (0.2f * k1[c]);
  f_sir(beta, gamma, tmp, k2);
#pragma unroll
  for (int c = 0; c < 3; ++c)
    tmp[c] = y[c] + dt * (0.075f * k1[c] + 0.225f * k2[c]);
  f_sir(beta, gamma, tmp, k3);
#pragma unroll
  for (int c = 0; c < 3; ++c)
    tmp[c] = y[c] + dt * ((44.0f / 45.0f) * k1[c] + (-56.0f / 15.0f) * k2[c] +
                          (32.0f / 9.0f) * k3[c]);
  f_sir(beta, gamma, tmp, k4);
#pragma unroll
  for (int c = 0; c < 3; ++c)
    tmp[c] = y[c] + dt * ((19372.0f / 6561.0f) * k1[c] +
                          (-25360.0f / 2187.0f) * k2[c] +
                          (64448.0f / 6561.0f) * k3[c] +
                          (-212.0f / 729.0f) * k4[c]);
  f_sir(beta, gamma, tmp, k5);
#pragma unroll
  for (int c = 0; c < 3; ++c)
    tmp[c] = y[c] + dt * ((9017.0f / 3168.0f) * k1[c] +
                          (-355.0f / 33.0f) * k2[c] +
                          (46732.0f / 5247.0f) * k3[c] +
                          (49.0f / 176.0f) * k4[c] +
                          (-5103.0f / 18656.0f) * k5[c]);
  f_sir(beta, gamma, tmp, k6);
#pragma unroll
  for (int c = 0; c < 3; ++c)
    y[c] = y[c] + dt * ((35.0f / 384.0f) * k1[c] +
                        (500.0f / 1113.0f) * k3[c] +
                        (125.0f / 192.0f) * k4[c] +
                        (-2187.0f / 6784.0f) * k5[c] +
                        (11.0f / 84.0f) * k6[c]);
}

// ---------------- Fused: enc1 (blocks 0..63) + W3 pack (blocks 64..191) ----
__global__ __launch_bounds__(256) void pre_kernel(
    const float* __restrict__ x, const float* __restrict__ w1,
    float* __restrict__ partial,
    const float* __restrict__ w3, unsigned short* __restrict__ Wt) {
  __shared__ __align__(16) float smem[128 * 65];  // 33 KB, shared by branches
  int tid = threadIdx.x;
  if (blockIdx.x < 64) {
    // ---- encoder layer 1 partial sums ----
    float4* sh = (float4*)smem;
    int j4 = tid & 31, kh = tid >> 5;
    int kbase = blockIdx.x * 128 + kh * 16;
    float4 a; a.x = 0.f; a.y = 0.f; a.z = 0.f; a.w = 0.f;
#pragma unroll
    for (int r = 0; r < 16; ++r) {
      int k = kbase + r;
      float xv = x[k];
      float4 wv = *(const float4*)(w1 + (size_t)k * 128 + j4 * 4);
      a.x = fmaf(xv, wv.x, a.x);
      a.y = fmaf(xv, wv.y, a.y);
      a.z = fmaf(xv, wv.z, a.z);
      a.w = fmaf(xv, wv.w, a.w);
    }
    sh[tid] = a;
    __syncthreads();
    if (tid < 32) {
      float4 s = sh[tid];
#pragma unroll
      for (int h = 1; h < 8; ++h) {
        float4 o = sh[h * 32 + tid];
        s.x += o.x; s.y += o.y; s.z += o.z; s.w += o.w;
      }
      *(float4*)(partial + blockIdx.x * 128 + tid * 4) = s;
    }
  } else {
    // ---- W3 pack (bf16 hi/lo, linear layout) ----
    float* tl = smem;
    int n0 = (blockIdx.x - 64) * 64;
#pragma unroll
    for (int e = 0; e < 32; ++e) {
      int idx = e * 256 + tid;
      int k = idx >> 6, c = idx & 63;
      tl[k * 65 + c] = w3[(size_t)k * 8192 + n0 + c];
    }
    __syncthreads();
    int nl = tid >> 2, q = tid & 3;
#pragma unroll
    for (int w = 0; w < 4; ++w) {
      int k0 = q * 32 + w * 8;
      short8_t vh, vl;
#pragma unroll
      for (int jj = 0; jj < 8; ++jj) {
        float v = tl[(k0 + jj) * 65 + nl];
        unsigned short h = f2bf_rn(v);
        vh[jj] = (short)h;
        vl[jj] = (short)f2bf_rn(v - bf2f(h));
      }
      *(short8_t*)(Wt + (size_t)(n0 + nl) * 256 + k0) = vh;
      *(short8_t*)(Wt + (size_t)(n0 + nl) * 256 + 128 + k0) = vl;
    }
  }
}

// ---------------- prep: enc2 + coarse ODE cascade -------------------------
__global__ __launch_bounds__(256) void prep_kernel(
    const float* __restrict__ partial, const float* __restrict__ b1,
    const float* __restrict__ w2, const float* __restrict__ b2,
    const float* __restrict__ w3, const float* __restrict__ b3,
    float* __restrict__ bg, float* __restrict__ ys) {
  __shared__ float h1s[128];
  __shared__ float h2s[64];
  __shared__ float bgs[2];
  __shared__ float Y0[16][3];
  __shared__ float Y1[256][3];
  int t = threadIdx.x;
  if (t < 128) {
    float s = b1[t];
    for (int b = 0; b < 64; ++b) s += partial[b * 128 + t];
    h1s[t] = fmaxf(s, 0.0f);
  }
  __syncthreads();
  if (t < 64) {
    float a = b2[t];
    for (int k = 0; k < 128; ++k) a = fmaf(h1s[k], w2[k * 64 + t], a);
    h2s[t] = fmaxf(a, 0.0f);
  }
  __syncthreads();
  if (t < 2) {
    float p = b3[t];
    for (int k = 0; k < 64; ++k) p = fmaf(h2s[k], w3[k * 2 + t], p);
    bgs[t] = p;
    bg[t] = p;
  }
  __syncthreads();
  float beta = bgs[0], gamma = bgs[1];
  if (t == 0) {
    float y[3] = {0.99f, 0.01f, 0.0f};
    Y0[0][0] = y[0]; Y0[0][1] = y[1]; Y0[0][2] = y[2];
    for (int j = 1; j < 16; ++j) {
      dopri5_step(beta, gamma, y, 512.0f * DT_C);
      Y0[j][0] = y[0]; Y0[j][1] = y[1]; Y0[j][2] = y[2];
    }
  }
  __syncthreads();
  if (t < 16) {
    float y[3] = {Y0[t][0], Y0[t][1], Y0[t][2]};
    Y1[t * 16][0] = y[0]; Y1[t * 16][1] = y[1]; Y1[t * 16][2] = y[2];
    for (int s = 1; s < 16; ++s) {
      dopri5_step(beta, gamma, y, 32.0f * DT_C);
      Y1[t * 16 + s][0] = y[0]; Y1[t * 16 + s][1] = y[1]; Y1[t * 16 + s][2] = y[2];
    }
  }
  __syncthreads();
  {
    float y[3] = {Y1[t][0], Y1[t][1], Y1[t][2]};
    ys[(t * 8) * 3 + 0] = y[0]; ys[(t * 8) * 3 + 1] = y[1]; ys[(t * 8) * 3 + 2] = y[2];
    for (int s = 1; s < 8; ++s) {
      dopri5_step(beta, gamma, y, 4.0f * DT_C);
      ys[(t * 8 + s) * 3 + 0] = y[0];
      ys[(t * 8 + s) * 3 + 1] = y[1];
      ys[(t * 8 + s) * 3 + 2] = y[2];
    }
  }
}

// ---------------- dec12f: fine ODE + decoder small layers + A pack --------
__global__ __launch_bounds__(256) void dec12f_kernel(
    const float* __restrict__ bg, const float* __restrict__ ys,
    const float* __restrict__ w1, const float* __restrict__ b1,
    const float* __restrict__ w2, const float* __restrict__ b2,
    unsigned short* __restrict__ Apack) {
  __shared__ float sols[128 * 4];
  __shared__ float w1s[192];
  __shared__ float b1s[64];
  __shared__ float b2s[128];
  __shared__ float h1s[128 * 66];
  int tid = threadIdx.x;
  int i0 = blockIdx.x * 128;
  if (tid < 192) w1s[tid] = w1[tid];
  if (tid < 64) b1s[tid] = b1[tid];
  if (tid < 128) b2s[tid] = b2[tid];
  if (tid < 33) {
    const float h = 0.25f * DT_C;
    float beta = bg[0], gamma = bg[1];
    int w = blockIdx.x * 32 + tid - 1;
    if (w < 0) {
      sols[0] = 0.99f; sols[1] = 0.01f; sols[2] = 0.0f;
    } else {
      float y[3] = {ys[w * 3 + 0], ys[w * 3 + 1], ys[w * 3 + 2]};
#pragma unroll
      for (int iv = 0; iv < 4; ++iv) {
        dopri5_step(beta, gamma, y, h);
        dopri5_step(beta, gamma, y, h);
        dopri5_step(beta, gamma, y, h);
        dopri5_step(beta, gamma, y, h);
        int local = 4 * w + iv + 1 - i0;
        if (local >= 0 && local < 128) {
          sols[local * 4 + 0] = y[0];
          sols[local * 4 + 1] = y[1];
          sols[local * 4 + 2] = y[2];
        }
      }
    }
  }
  __syncthreads();
#pragma unroll
  for (int e = 0; e < 32; ++e) {
    int idx = e * 256 + tid;
    int i = idx >> 6, j = idx & 63;
    float v = b1s[j];
    v = fmaf(sols[i * 4 + 0], w1s[j], v);
    v = fmaf(sols[i * 4 + 1], w1s[64 + j], v);
    v = fmaf(sols[i * 4 + 2], w1s[128 + j], v);
    h1s[i * 66 + j] = fmaxf(v, 0.0f);
  }
  __syncthreads();
  int tx = tid & 15, ty = tid >> 4;
  float acc[8][8];
#pragma unroll
  for (int a = 0; a < 8; ++a)
#pragma unroll
    for (int b = 0; b < 8; ++b) acc[a][b] = 0.0f;
  for (int j = 0; j < 64; ++j) {
    float a[8];
#pragma unroll
    for (int mm = 0; mm < 8; ++mm) a[mm] = h1s[(ty * 8 + mm) * 66 + j];
    float4 q0 = *(const float4*)(w2 + j * 128 + tx * 8);
    float4 q1 = *(const float4*)(w2 + j * 128 + tx * 8 + 4);
    float b[8] = {q0.x, q0.y, q0.z, q0.w, q1.x, q1.y, q1.z, q1.w};
#pragma unroll
    for (int mm = 0; mm < 8; ++mm)
#pragma unroll
      for (int nn = 0; nn < 8; ++nn)
        acc[mm][nn] = fmaf(a[mm], b[nn], acc[mm][nn]);
  }
#pragma unroll
  for (int mm = 0; mm < 8; ++mm) {
    int row = i0 + ty * 8 + mm;
    short8_t vh, vl;
#pragma unroll
    for (int nn = 0; nn < 8; ++nn) {
      float v = fmaxf(acc[mm][nn] + b2s[tx * 8 + nn], 0.0f);
      unsigned short h = f2bf_rn(v);
      vh[nn] = (short)h;
      vl[nn] = (short)f2bf_rn(v - bf2f(h));
    }
    *(short8_t*)(Apack + (size_t)row * 256 + tx * 8) = vh;
    *(short8_t*)(Apack + (size_t)row * 256 + 128 + tx * 8) = vl;
  }
}

// ---------------- Big GEMM (bf16 split MFMA, 256^2 tile, 2-phase dbuf) ----
// out = relu(h2 @ W3 + b3) via Ahi*Bhi + Ahi*Blo + Alo*Bhi.
// A=Apack[8192][256], B=Wt[8192][256] (hi[128] | lo[128] shorts per row).
// 8 waves (2M x 4N), wave tile 128x64, frags 16x16x32. K = 4 chunks of 32,
// double-buffered: STAGE(c+1) issued before compute of c; one barrier/chunk.
// Row = 4 slots of 8 shorts; logical group g stored at slot g^(r&3).
__global__ __launch_bounds__(512, 2) void gemm_bf16_kernel(
    const unsigned short* __restrict__ A, const unsigned short* __restrict__ B,
    const float* __restrict__ bias, float* __restrict__ out) {
  __shared__ unsigned short Ah[2][256 * 32];
  __shared__ unsigned short Al[2][256 * 32];
  __shared__ unsigned short Bh[2][256 * 32];
  __shared__ unsigned short Bl[2][256 * 32];
  int tid = threadIdx.x;
  int bid = blockIdx.x;
  int swz = (bid & 7) * 128 + (bid >> 3);   // bijective, 1024 % 8 == 0
  int by = swz & 31, bx = swz >> 5;         // each XCD: 4 n-panels, all m
  int m0 = by * 256;
  int n0 = bx * 256;
  int lane = tid & 63, wave = tid >> 6;     // 8 waves
  int wm = (wave >> 2) * 128, wn = (wave & 3) * 64;
  int lrow = lane & 15, lgrp = lane >> 4;
  int lr4 = lane >> 2, lp = lane & 3;       // staging: row-in-16, slot

  f32x4 acc[8][4];
  f32x4 z = {0.0f, 0.0f, 0.0f, 0.0f};
#pragma unroll
  for (int mi = 0; mi < 8; ++mi)
#pragma unroll
    for (int ni = 0; ni < 4; ++ni) acc[mi][ni] = z;

  auto STAGE = [&](int buf, int c) {
    int kin = c * 32;
#pragma unroll
    for (int i = 0; i < 2; ++i) {
      int seg = wave * 2 + i;           // 16 segments of 16 rows
      int r = seg * 16 + lr4;           // tile row this lane fetches
      int g = lp ^ (r & 3);             // logical group for slot lp
      const unsigned short* ar = A + (size_t)(m0 + r) * 256 + kin + g * 8;
      const unsigned short* br = B + (size_t)(n0 + r) * 256 + kin + g * 8;
      gl2lds16(ar,       &Ah[buf][seg * 512]);
      gl2lds16(ar + 128, &Al[buf][seg * 512]);
      gl2lds16(br,       &Bh[buf][seg * 512]);
      gl2lds16(br + 128, &Bl[buf][seg * 512]);
    }
  };

  STAGE(0, 0);
  __syncthreads();  // implicit vmcnt(0) drain

#pragma unroll
  for (int c = 0; c < 4; ++c) {
    int cur = c & 1;
    if (c < 3) STAGE(cur ^ 1, c + 1);  // issue next-chunk loads first

    short8_t ah[8], bh[4];
#pragma unroll
    for (int mi = 0; mi < 8; ++mi) {
      int r = wm + mi * 16 + lrow;
      int p = lgrp ^ (r & 3);
      ah[mi] = *(const short8_t*)(&Ah[cur][r * 32 + p * 8]);
    }
#pragma unroll
    for (int ni = 0; ni < 4; ++ni) {
      int r = wn + ni * 16 + lrow;
      int p = lgrp ^ (r & 3);
      bh[ni] = *(const short8_t*)(&Bh[cur][r * 32 + p * 8]);
    }
    // pass 0: Ahi x Bhi
#pragma unroll
    for (int mi = 0; mi < 8; ++mi)
#pragma unroll
      for (int ni = 0; ni < 4; ++ni)
        acc[mi][ni] = __builtin_amdgcn_mfma_f32_16x16x32_bf16(
            ah[mi], bh[ni], acc[mi][ni], 0, 0, 0);
    // pass 1: Ahi x Blo (reuse ah)
    {
      short8_t bl[4];
#pragma unroll
      for (int ni = 0; ni < 4; ++ni) {
        int r = wn + ni * 16 + lrow;
        int p = lgrp ^ (r & 3);
        bl[ni] = *(const short8_t*)(&Bl[cur][r * 32 + p * 8]);
      }
#pragma unroll
      for (int mi = 0; mi < 8; ++mi)
#pragma unroll
        for (int ni = 0; ni < 4; ++ni)
          acc[mi][ni] = __builtin_amdgcn_mfma_f32_16x16x32_bf16(
              ah[mi], bl[ni], acc[mi][ni], 0, 0, 0);
    }
    // pass 2: Alo x Bhi (reuse bh)
    {
      short8_t al[8];
#pragma unroll
      for (int mi = 0; mi < 8; ++mi) {
        int r = wm + mi * 16 + lrow;
        int p = lgrp ^ (r & 3);
        al[mi] = *(const short8_t*)(&Al[cur][r * 32 + p * 8]);
      }
#pragma unroll
      for (int mi = 0; mi < 8; ++mi)
#pragma unroll
        for (int ni = 0; ni < 4; ++ni)
          acc[mi][ni] = __builtin_amdgcn_mfma_f32_16x16x32_bf16(
              al[mi], bh[ni], acc[mi][ni], 0, 0, 0);
    }
    if (c < 3) __syncthreads();  // drains next-chunk stage; protects buffers
  }

  float bv[4];
#pragma unroll
  for (int ni = 0; ni < 4; ++ni) bv[ni] = bias[n0 + wn + ni * 16 + lrow];
#pragma unroll
  for (int mi = 0; mi < 8; ++mi)
#pragma unroll
    for (int ni = 0; ni < 4; ++ni) {
      int col = n0 + wn + ni * 16 + lrow;
#pragma unroll
      for (int r = 0; r < 4; ++r) {
        int row = m0 + wm + mi * 16 + lgrp * 4 + r;
        out[(size_t)row * 8192 + col] = fmaxf(acc[mi][ni][r] + bv[ni], 0.0f);
      }
    }
}

// ---------------- Launch --------------------------------------------------

extern "C" void kernel_launch(void* const* d_in, const int* in_sizes, int n_in,
                              void* d_out, int out_size, void* d_ws, size_t ws_size,
                              hipStream_t stream) {
  const float* x      = (const float*)d_in[0];
  const float* enc_w1 = (const float*)d_in[2];
  const float* enc_b1 = (const float*)d_in[3];
  const float* enc_w2 = (const float*)d_in[4];
  const float* enc_b2 = (const float*)d_in[5];
  const float* enc_w3 = (const float*)d_in[6];
  const float* enc_b3 = (const float*)d_in[7];
  const float* dec_w1 = (const float*)d_in[8];
  const float* dec_b1 = (const float*)d_in[9];
  const float* dec_w2 = (const float*)d_in[10];
  const float* dec_b2 = (const float*)d_in[11];
  const float* dec_w3 = (const float*)d_in[12];
  const float* dec_b3 = (const float*)d_in[13];
  float* out = (float*)d_out;

  // ws layout: bg[2] @0, partial[64*128] @64, ys[2048*3] @8320 (floats);
  // Apack 4 MB @ byte 65536; Wt 4 MB @ byte 4259840. Total ~8.26 MB.
  float* ws      = (float*)d_ws;
  float* bg      = ws;
  float* partial = ws + 64;
  float* ys      = ws + 8320;
  unsigned short* Apack = (unsigned short*)((char*)d_ws + 65536);
  unsigned short* Wt    = (unsigned short*)((char*)d_ws + 65536 + 4194304);

  hipLaunchKernelGGL(pre_kernel, dim3(192), dim3(256), 0, stream,
                     x, enc_w1, partial, dec_w3, Wt);
  hipLaunchKernelGGL(prep_kernel, dim3(1), dim3(256), 0, stream,
                     partial, enc_b1, enc_w2, enc_b2, enc_w3, enc_b3, bg, ys);
  hipLaunchKernelGGL(dec12f_kernel, dim3(64), dim3(256), 0, stream,
                     bg, ys, dec_w1, dec_b1, dec_w2, dec_b2, Apack);
  hipLaunchKernelGGL(gemm_bf16_kernel, dim3(1024), dim3(512), 0, stream,
                     Apack, Wt, dec_b3, out);
}